// Round 5
// baseline (1438.983 us; speedup 1.0000x reference)
//
#include <hip/hip_runtime.h>
#include <hip/hip_bf16.h>

#define C 64  // channels

// ---------------------------------------------------------------------------
// Fused MLP: h0 = relu(relu(x @ W1) @ W2), row-major [nN][64].
// Block = 256 threads -> 64 rows x 64 cols, 4x4 microtile/thread.
// BK=64 with register-prefetch double buffering (global loads overlap FMAs).
// ---------------------------------------------------------------------------
__launch_bounds__(256)
__global__ void mlp_kernel(const float* __restrict__ x,
                           const float* __restrict__ W1,
                           const float* __restrict__ W2,
                           float* __restrict__ h0, int nN)
{
    __shared__ float smem[8704];                     // 34816 B
    float (*As)[68] = (float(*)[68])smem;            // [64 rows][k 0..63]
    float (*Bs)[68] = (float(*)[68])(smem + 4352);   // [64 k][c 0..63]
    float (*Hs)[68] = As;                            // phase 2 aliases
    float (*Ws)[68] = Bs;

    const int t  = threadIdx.x;
    const int ty = t >> 4;          // rows 4*ty..4*ty+3
    const int tx = t & 15;          // cols 4*tx..4*tx+3
    const int row0 = blockIdx.x * 64;

    float acc[4][4] = {};
    float4 pa[4], pb[4];

    // prefetch tile k0=0: A 64x64 + B 64x64, 4 float4 each per thread
    #pragma unroll
    for (int h = 0; h < 4; ++h) {
        int f = t + 256 * h;
        int r  = f >> 4;            // 0..63
        int lk = (f & 15) * 4;      // 0..60
        int grow = row0 + r;
        pa[h] = make_float4(0.f, 0.f, 0.f, 0.f);
        if (grow < nN) pa[h] = *(const float4*)&x[(size_t)grow * 512 + lk];
        pb[h] = *(const float4*)&W1[(size_t)r * 64 + lk];
    }

    for (int k0 = 0; k0 < 512; k0 += 64) {
        // commit prefetched tile to LDS
        #pragma unroll
        for (int h = 0; h < 4; ++h) {
            int f = t + 256 * h;
            int r  = f >> 4;
            int lk = (f & 15) * 4;
            *(float4*)&As[r][lk] = pa[h];
            *(float4*)&Bs[r][lk] = pb[h];
        }
        __syncthreads();

        // issue next tile's loads (overlap with compute below)
        int k1 = k0 + 64;
        if (k1 < 512) {
            #pragma unroll
            for (int h = 0; h < 4; ++h) {
                int f = t + 256 * h;
                int r  = f >> 4;
                int lk = (f & 15) * 4;
                int grow = row0 + r;
                pa[h] = make_float4(0.f, 0.f, 0.f, 0.f);
                if (grow < nN) pa[h] = *(const float4*)&x[(size_t)grow * 512 + k1 + lk];
                pb[h] = *(const float4*)&W1[(size_t)(k1 + r) * 64 + lk];
            }
        }

        // compute 64 k-steps
        for (int kk = 0; kk < 64; kk += 4) {
            float4 b0 = *(float4*)&Bs[kk + 0][tx * 4];
            float4 b1 = *(float4*)&Bs[kk + 1][tx * 4];
            float4 b2 = *(float4*)&Bs[kk + 2][tx * 4];
            float4 b3 = *(float4*)&Bs[kk + 3][tx * 4];
            #pragma unroll
            for (int i = 0; i < 4; ++i) {
                float4 a = *(float4*)&As[ty * 4 + i][kk];
                acc[i][0] += a.x * b0.x + a.y * b1.x + a.z * b2.x + a.w * b3.x;
                acc[i][1] += a.x * b0.y + a.y * b1.y + a.z * b2.y + a.w * b3.y;
                acc[i][2] += a.x * b0.z + a.y * b1.z + a.z * b2.z + a.w * b3.z;
                acc[i][3] += a.x * b0.w + a.y * b1.w + a.z * b2.w + a.w * b3.w;
            }
        }
        __syncthreads();
    }

    // phase 2: h1 (relu) into Hs (k-contig rows), W2 into Ws
    #pragma unroll
    for (int i = 0; i < 4; ++i) {
        float4 o;
        o.x = acc[i][0] > 0.f ? acc[i][0] : 0.f;
        o.y = acc[i][1] > 0.f ? acc[i][1] : 0.f;
        o.z = acc[i][2] > 0.f ? acc[i][2] : 0.f;
        o.w = acc[i][3] > 0.f ? acc[i][3] : 0.f;
        *(float4*)&Hs[ty * 4 + i][tx * 4] = o;
    }
    #pragma unroll
    for (int h = 0; h < 4; ++h) {
        int f = t + 256 * h;
        int kr = f >> 4;
        int c4 = (f & 15) * 4;
        *(float4*)&Ws[kr][c4] = *(const float4*)&W2[(size_t)kr * 64 + c4];
    }
    __syncthreads();

    float acc2[4][4] = {};
    for (int kk = 0; kk < 64; kk += 4) {
        float4 b0 = *(float4*)&Ws[kk + 0][tx * 4];
        float4 b1 = *(float4*)&Ws[kk + 1][tx * 4];
        float4 b2 = *(float4*)&Ws[kk + 2][tx * 4];
        float4 b3 = *(float4*)&Ws[kk + 3][tx * 4];
        #pragma unroll
        for (int i = 0; i < 4; ++i) {
            float4 a = *(float4*)&Hs[ty * 4 + i][kk];
            acc2[i][0] += a.x * b0.x + a.y * b1.x + a.z * b2.x + a.w * b3.x;
            acc2[i][1] += a.x * b0.y + a.y * b1.y + a.z * b2.y + a.w * b3.y;
            acc2[i][2] += a.x * b0.z + a.y * b1.z + a.z * b2.z + a.w * b3.z;
            acc2[i][3] += a.x * b0.w + a.y * b1.w + a.z * b2.w + a.w * b3.w;
        }
    }

    #pragma unroll
    for (int i = 0; i < 4; ++i) {
        int grow = row0 + ty * 4 + i;
        if (grow < nN) {
            float4 o;
            o.x = acc2[i][0] > 0.f ? acc2[i][0] : 0.f;
            o.y = acc2[i][1] > 0.f ? acc2[i][1] : 0.f;
            o.z = acc2[i][2] > 0.f ? acc2[i][2] : 0.f;
            o.w = acc2[i][3] > 0.f ? acc2[i][3] : 0.f;
            *(float4*)&h0[(size_t)grow * 64 + tx * 4] = o;
        }
    }
}

// ---------------------------------------------------------------------------
// CSR build: degree count -> single-block scan -> atomic fill (packed col+wgt).
// After fill, rowptr[n] = END offset; start = rowptr[n-1] (0 for n=0).
// ---------------------------------------------------------------------------
__launch_bounds__(256)
__global__ void count_kernel(const int* __restrict__ dst, int* __restrict__ rowptr, int nE)
{
    int e = blockIdx.x * 256 + threadIdx.x;
    if (e < nE) atomicAdd(&rowptr[dst[e]], 1);
}

__launch_bounds__(1024)
__global__ void scan_kernel(int* __restrict__ deg, int nN)
{
    __shared__ int sums[1024];
    const int t = threadIdx.x;
    const int len = (nN + 1023) / 1024;
    const int lo = t * len;
    const int hi = min(nN, lo + len);
    int s = 0;
    for (int i = lo; i < hi; ++i) s += deg[i];
    sums[t] = s;
    __syncthreads();
    for (int d = 1; d < 1024; d <<= 1) {
        int v = (t >= d) ? sums[t - d] : 0;
        __syncthreads();
        sums[t] += v;
        __syncthreads();
    }
    int off = sums[t] - s;
    for (int i = lo; i < hi; ++i) {
        int d = deg[i];
        deg[i] = off;
        off += d;
    }
}

__launch_bounds__(256)
__global__ void fill_kernel(const int* __restrict__ src, const int* __restrict__ dst,
                            const float* __restrict__ w,
                            int* __restrict__ rowptr,
                            int2* __restrict__ cwp, int nE)
{
    int e = blockIdx.x * 256 + threadIdx.x;
    if (e >= nE) return;
    int d = dst[e];
    int pos = atomicAdd(&rowptr[d], 1);
    cwp[pos] = make_int2(src[e], __float_as_int(w[e]));
}

// ---------------------------------------------------------------------------
// Fused pull-SpMM + gate.  One wave per dst node (or per output index).
// 4 edge groups x 16 lanes x float4; 4 edges unrolled per group = 16 edges
// in flight per wave.  Blocks [0, nodeBlocks) write nxt; blocks beyond
// recompute the indexed rows from cur and accumulate gate*row into out.
// ---------------------------------------------------------------------------
__launch_bounds__(256)
__global__ void spmm_fused(const int* __restrict__ rowptr,
                           const int2* __restrict__ cwp,
                           const float* __restrict__ cur,
                           float* __restrict__ nxt,
                           const int* __restrict__ idx,
                           const float* __restrict__ wp,
                           float* __restrict__ out,
                           int nN, int nI, int nodeBlocks)
{
    const int bid  = blockIdx.x;
    const int wid  = threadIdx.x >> 6;
    const int lane = threadIdx.x & 63;
    const int g = lane >> 4;   // edge sub-slot 0..3
    const int q = lane & 15;   // channel quad

    int node, oi = -1;
    if (bid < nodeBlocks) {
        node = bid * 4 + wid;
        if (node >= nN) return;
    } else {
        oi = (bid - nodeBlocks) * 4 + wid;
        if (oi >= nI) return;
        node = idx[oi];
    }

    const int beg = (node == 0) ? 0 : rowptr[node - 1];
    const int end = rowptr[node];

    float4 A0 = make_float4(0.f,0.f,0.f,0.f);
    float4 A1 = make_float4(0.f,0.f,0.f,0.f);
    float4 A2 = make_float4(0.f,0.f,0.f,0.f);
    float4 A3 = make_float4(0.f,0.f,0.f,0.f);

    int e = beg + g;
    for (; e + 12 < end; e += 16) {
        int2 c0 = cwp[e];
        int2 c1 = cwp[e + 4];
        int2 c2 = cwp[e + 8];
        int2 c3 = cwp[e + 12];
        float4 v0 = *(const float4*)&cur[(size_t)c0.x * 64 + q * 4];
        float4 v1 = *(const float4*)&cur[(size_t)c1.x * 64 + q * 4];
        float4 v2 = *(const float4*)&cur[(size_t)c2.x * 64 + q * 4];
        float4 v3 = *(const float4*)&cur[(size_t)c3.x * 64 + q * 4];
        float w0 = __int_as_float(c0.y), w1 = __int_as_float(c1.y);
        float w2 = __int_as_float(c2.y), w3 = __int_as_float(c3.y);
        A0.x += w0*v0.x; A0.y += w0*v0.y; A0.z += w0*v0.z; A0.w += w0*v0.w;
        A1.x += w1*v1.x; A1.y += w1*v1.y; A1.z += w1*v1.z; A1.w += w1*v1.w;
        A2.x += w2*v2.x; A2.y += w2*v2.y; A2.z += w2*v2.z; A2.w += w2*v2.w;
        A3.x += w3*v3.x; A3.y += w3*v3.y; A3.z += w3*v3.z; A3.w += w3*v3.w;
    }
    for (; e < end; e += 4) {
        int2 c0 = cwp[e];
        float4 v0 = *(const float4*)&cur[(size_t)c0.x * 64 + q * 4];
        float w0 = __int_as_float(c0.y);
        A0.x += w0*v0.x; A0.y += w0*v0.y; A0.z += w0*v0.z; A0.w += w0*v0.w;
    }
    A0.x += A1.x + A2.x + A3.x;
    A0.y += A1.y + A2.y + A3.y;
    A0.z += A1.z + A2.z + A3.z;
    A0.w += A1.w + A2.w + A3.w;

    // reduce across the 4 edge groups (lanes differing in bits 4,5)
    A0.x += __shfl_xor(A0.x, 16); A0.y += __shfl_xor(A0.y, 16);
    A0.z += __shfl_xor(A0.z, 16); A0.w += __shfl_xor(A0.w, 16);
    A0.x += __shfl_xor(A0.x, 32); A0.y += __shfl_xor(A0.y, 32);
    A0.z += __shfl_xor(A0.z, 32); A0.w += __shfl_xor(A0.w, 32);

    if (oi < 0) {
        if (g == 0)
            *(float4*)&nxt[(size_t)node * 64 + q * 4] = A0;
    } else {
        // gate: s = row . wp  (reduce partial dot across the 16 q-lanes)
        float s = A0.x * wp[q * 4] + A0.y * wp[q * 4 + 1]
                + A0.z * wp[q * 4 + 2] + A0.w * wp[q * 4 + 3];
        s += __shfl_xor(s, 1); s += __shfl_xor(s, 2);
        s += __shfl_xor(s, 4); s += __shfl_xor(s, 8);
        float gate = 1.f / (1.f + __expf(-s));
        if (g == 0) {
            float* op = &out[(size_t)oi * 64 + q * 4];
            float4 prev = *(float4*)op;
            prev.x += gate * A0.x; prev.y += gate * A0.y;
            prev.z += gate * A0.z; prev.w += gate * A0.w;
            *(float4*)op = prev;
        }
    }
}

// ---------------------------------------------------------------------------
// Hop-0 gate: out[i] = sigmoid(h[idx[i]].wp) * h[idx[i]]  (initializes out)
// ---------------------------------------------------------------------------
__launch_bounds__(256)
__global__ void gate_gather(const float* __restrict__ h,
                            const int* __restrict__ idx,
                            const float* __restrict__ wp,
                            float* __restrict__ out, int nI)
{
    int gid = blockIdx.x * 256 + threadIdx.x;
    int i = gid >> 6;
    if (i >= nI) return;
    int c = gid & 63;
    int n = idx[i];
    float v = h[(size_t)n * 64 + c];
    float s = v * wp[c];
    #pragma unroll
    for (int off = 32; off > 0; off >>= 1)
        s += __shfl_xor(s, off);
    float gate = 1.f / (1.f + __expf(-s));
    out[gid] = gate * v;
}

extern "C" void kernel_launch(void* const* d_in, const int* in_sizes, int n_in,
                              void* d_out, int out_size, void* d_ws, size_t ws_size,
                              hipStream_t stream) {
    const float* x    = (const float*)d_in[0];
    const int*   esrc = (const int*)d_in[1];
    const int*   edst = (const int*)d_in[2];
    const float* ew   = (const float*)d_in[3];
    const int*   nidx = (const int*)d_in[4];
    const float* W1   = (const float*)d_in[5];
    const float* W2   = (const float*)d_in[6];
    const float* wp   = (const float*)d_in[7];
    float* out = (float*)d_out;

    const int nN = in_sizes[0] / 512;
    const int nE = in_sizes[1];
    const int nI = in_sizes[4];

    // ws layout: bufA 25.6M | bufB 25.6M | rowptr 0.4M | cwp 12.8M  (= 64.4 MB)
    float* bufA   = (float*)d_ws;
    float* bufB   = bufA + (size_t)nN * C;
    int*   rowptr = (int*)(bufB + (size_t)nN * C);
    int2*  cwp    = (int2*)(rowptr + nN);

    // --- CSR build (by dst) ---
    hipMemsetAsync(rowptr, 0, (size_t)nN * sizeof(int), stream);
    count_kernel<<<(nE + 255) / 256, 256, 0, stream>>>(edst, rowptr, nE);
    scan_kernel<<<1, 1024, 0, stream>>>(rowptr, nN);
    fill_kernel<<<(nE + 255) / 256, 256, 0, stream>>>(esrc, edst, ew, rowptr, cwp, nE);

    // --- MLP ---
    mlp_kernel<<<(nN + 63) / 64, 256, 0, stream>>>(x, W1, W2, bufA, nN);

    // hop 0 gate (initializes out)
    gate_gather<<<(nI * 64 + 255) / 256, 256, 0, stream>>>(bufA, nidx, wp, out, nI);

    float* cur = bufA;
    float* nxt = bufB;
    const int nodeBlocks = (nN + 3) / 4;
    const int idxBlocks  = (nI + 3) / 4;
    for (int k = 0; k < 10; ++k) {
        spmm_fused<<<nodeBlocks + idxBlocks, 256, 0, stream>>>(
            rowptr, cwp, cur, nxt, nidx, wp, out, nN, nI, nodeBlocks);
        float* tmp = cur; cur = nxt; nxt = tmp;
    }
}

// Round 6
// 1297.011 us; speedup vs baseline: 1.1095x; 1.1095x over previous
//
#include <hip/hip_runtime.h>
#include <hip/hip_bf16.h>

#define C 64  // channels

// bf16 <-> f32 helpers (bit-level, RNE on pack)
__device__ __forceinline__ float b2f(unsigned short s) {
    return __uint_as_float(((unsigned int)s) << 16);
}
__device__ __forceinline__ unsigned short f2b(float f) {
    unsigned int u = __float_as_uint(f);
    u = (u + 0x7FFF + ((u >> 16) & 1)) >> 16;
    return (unsigned short)u;
}
__device__ __forceinline__ float4 bf4(ushort4 u) {
    return make_float4(b2f(u.x), b2f(u.y), b2f(u.z), b2f(u.w));
}

// ---------------------------------------------------------------------------
// Fused MLP: h = relu(relu(x @ W1) @ W2).
// Writes BOTH fp32 h0 (hop-0 gate) and bf16 hb (propagation seed).
// R4-proven structure: BK=32 single-buffered, row-major LDS, 4x4 microtile.
// ---------------------------------------------------------------------------
__launch_bounds__(256)
__global__ void mlp_kernel(const float* __restrict__ x,
                           const float* __restrict__ W1,
                           const float* __restrict__ W2,
                           float* __restrict__ h0,
                           unsigned short* __restrict__ hb, int nN)
{
    __shared__ float smem[8704];
    float (*As)[36] = (float(*)[36])smem;            // 2304 floats
    float (*Bs)[68] = (float(*)[68])(smem + 2304);   // 2176 floats
    float (*Hs)[68] = (float(*)[68])smem;            // 4352 floats
    float (*Ws)[68] = (float(*)[68])(smem + 4352);   // 4352 floats

    const int t  = threadIdx.x;
    const int ty = t >> 4;
    const int tx = t & 15;
    const int row0 = blockIdx.x * 64;

    float acc[4][4] = {};

    for (int k0 = 0; k0 < 512; k0 += 32) {
        #pragma unroll
        for (int h = 0; h < 2; ++h) {
            int f = t + 256 * h;
            int r  = f >> 3;
            int lk = (f & 7) * 4;
            int grow = row0 + r;
            float4 v = make_float4(0.f, 0.f, 0.f, 0.f);
            if (grow < nN)
                v = *(const float4*)&x[(size_t)grow * 512 + k0 + lk];
            *(float4*)&As[r][lk] = v;
        }
        #pragma unroll
        for (int h = 0; h < 2; ++h) {
            int f = t + 256 * h;
            int kr = f >> 4;
            int c4 = (f & 15) * 4;
            *(float4*)&Bs[kr][c4] = *(const float4*)&W1[(size_t)(k0 + kr) * 64 + c4];
        }
        __syncthreads();

        for (int kk = 0; kk < 32; kk += 4) {
            float4 b0 = *(float4*)&Bs[kk + 0][tx * 4];
            float4 b1 = *(float4*)&Bs[kk + 1][tx * 4];
            float4 b2 = *(float4*)&Bs[kk + 2][tx * 4];
            float4 b3 = *(float4*)&Bs[kk + 3][tx * 4];
            #pragma unroll
            for (int i = 0; i < 4; ++i) {
                float4 a = *(float4*)&As[ty * 4 + i][kk];
                acc[i][0] += a.x * b0.x + a.y * b1.x + a.z * b2.x + a.w * b3.x;
                acc[i][1] += a.x * b0.y + a.y * b1.y + a.z * b2.y + a.w * b3.y;
                acc[i][2] += a.x * b0.z + a.y * b1.z + a.z * b2.z + a.w * b3.z;
                acc[i][3] += a.x * b0.w + a.y * b1.w + a.z * b2.w + a.w * b3.w;
            }
        }
        __syncthreads();
    }

    #pragma unroll
    for (int i = 0; i < 4; ++i) {
        float4 o;
        o.x = acc[i][0] > 0.f ? acc[i][0] : 0.f;
        o.y = acc[i][1] > 0.f ? acc[i][1] : 0.f;
        o.z = acc[i][2] > 0.f ? acc[i][2] : 0.f;
        o.w = acc[i][3] > 0.f ? acc[i][3] : 0.f;
        *(float4*)&Hs[ty * 4 + i][tx * 4] = o;
    }
    #pragma unroll
    for (int q = 0; q < 4; ++q) {
        int f = t + 256 * q;
        int kr = f >> 4;
        int c4 = (f & 15) * 4;
        *(float4*)&Ws[kr][c4] = *(const float4*)&W2[(size_t)kr * 64 + c4];
    }
    __syncthreads();

    float acc2[4][4] = {};
    for (int kk = 0; kk < 64; kk += 4) {
        float4 b0 = *(float4*)&Ws[kk + 0][tx * 4];
        float4 b1 = *(float4*)&Ws[kk + 1][tx * 4];
        float4 b2 = *(float4*)&Ws[kk + 2][tx * 4];
        float4 b3 = *(float4*)&Ws[kk + 3][tx * 4];
        #pragma unroll
        for (int i = 0; i < 4; ++i) {
            float4 a = *(float4*)&Hs[ty * 4 + i][kk];
            acc2[i][0] += a.x * b0.x + a.y * b1.x + a.z * b2.x + a.w * b3.x;
            acc2[i][1] += a.x * b0.y + a.y * b1.y + a.z * b2.y + a.w * b3.y;
            acc2[i][2] += a.x * b0.z + a.y * b1.z + a.z * b2.z + a.w * b3.z;
            acc2[i][3] += a.x * b0.w + a.y * b1.w + a.z * b2.w + a.w * b3.w;
        }
    }

    #pragma unroll
    for (int i = 0; i < 4; ++i) {
        int grow = row0 + ty * 4 + i;
        if (grow < nN) {
            float4 o;
            o.x = acc2[i][0] > 0.f ? acc2[i][0] : 0.f;
            o.y = acc2[i][1] > 0.f ? acc2[i][1] : 0.f;
            o.z = acc2[i][2] > 0.f ? acc2[i][2] : 0.f;
            o.w = acc2[i][3] > 0.f ? acc2[i][3] : 0.f;
            *(float4*)&h0[(size_t)grow * 64 + tx * 4] = o;
            ushort4 ob = make_ushort4(f2b(o.x), f2b(o.y), f2b(o.z), f2b(o.w));
            *(ushort4*)&hb[(size_t)grow * 64 + tx * 4] = ob;
        }
    }
}

// ---------------------------------------------------------------------------
// CSR build: degree count -> single-block scan -> atomic fill (packed col+wgt).
// After fill, rowptr[n] = END offset; start = rowptr[n-1] (0 for n=0).
// ---------------------------------------------------------------------------
__launch_bounds__(256)
__global__ void count_kernel(const int* __restrict__ dst, int* __restrict__ rowptr, int nE)
{
    int e = blockIdx.x * 256 + threadIdx.x;
    if (e < nE) atomicAdd(&rowptr[dst[e]], 1);
}

__launch_bounds__(1024)
__global__ void scan_kernel(int* __restrict__ deg, int nN)
{
    __shared__ int sums[1024];
    const int t = threadIdx.x;
    const int len = (nN + 1023) / 1024;
    const int lo = t * len;
    const int hi = min(nN, lo + len);
    int s = 0;
    for (int i = lo; i < hi; ++i) s += deg[i];
    sums[t] = s;
    __syncthreads();
    for (int d = 1; d < 1024; d <<= 1) {
        int v = (t >= d) ? sums[t - d] : 0;
        __syncthreads();
        sums[t] += v;
        __syncthreads();
    }
    int off = sums[t] - s;
    for (int i = lo; i < hi; ++i) {
        int d = deg[i];
        deg[i] = off;
        off += d;
    }
}

__launch_bounds__(256)
__global__ void fill_kernel(const int* __restrict__ src, const int* __restrict__ dst,
                            const float* __restrict__ w,
                            int* __restrict__ rowptr,
                            int2* __restrict__ cwp, int nE)
{
    int e = blockIdx.x * 256 + threadIdx.x;
    if (e >= nE) return;
    int d = dst[e];
    int pos = atomicAdd(&rowptr[d], 1);
    cwp[pos] = make_int2(src[e], __float_as_int(w[e]));
}

// ---------------------------------------------------------------------------
// Fused pull-SpMM + gate, bf16 propagation.  One wave per dst node (or per
// output index).  4 edge groups x 16 lanes x ushort4 (8B = 4 bf16 ch each);
// 4 edges unrolled per group = 16 edges in flight.  fp32 accumulate.
// Node blocks write bf16 nxt; idx-tail blocks gate fp32 row into out.
// ---------------------------------------------------------------------------
__launch_bounds__(256)
__global__ void spmm_fused(const int* __restrict__ rowptr,
                           const int2* __restrict__ cwp,
                           const unsigned short* __restrict__ cur,
                           unsigned short* __restrict__ nxt,
                           const int* __restrict__ idx,
                           const float* __restrict__ wp,
                           float* __restrict__ out,
                           int nN, int nI, int nodeBlocks)
{
    const int bid  = blockIdx.x;
    const int wid  = threadIdx.x >> 6;
    const int lane = threadIdx.x & 63;
    const int g = lane >> 4;   // edge sub-slot 0..3
    const int q = lane & 15;   // channel quad

    int node, oi = -1;
    if (bid < nodeBlocks) {
        node = bid * 4 + wid;
        if (node >= nN) return;
    } else {
        oi = (bid - nodeBlocks) * 4 + wid;
        if (oi >= nI) return;
        node = idx[oi];
    }

    const int beg = (node == 0) ? 0 : rowptr[node - 1];
    const int end = rowptr[node];

    float4 A0 = make_float4(0.f,0.f,0.f,0.f);
    float4 A1 = make_float4(0.f,0.f,0.f,0.f);
    float4 A2 = make_float4(0.f,0.f,0.f,0.f);
    float4 A3 = make_float4(0.f,0.f,0.f,0.f);

    int e = beg + g;
    for (; e + 12 < end; e += 16) {
        int2 c0 = cwp[e];
        int2 c1 = cwp[e + 4];
        int2 c2 = cwp[e + 8];
        int2 c3 = cwp[e + 12];
        float4 v0 = bf4(*(const ushort4*)&cur[(size_t)c0.x * 64 + q * 4]);
        float4 v1 = bf4(*(const ushort4*)&cur[(size_t)c1.x * 64 + q * 4]);
        float4 v2 = bf4(*(const ushort4*)&cur[(size_t)c2.x * 64 + q * 4]);
        float4 v3 = bf4(*(const ushort4*)&cur[(size_t)c3.x * 64 + q * 4]);
        float w0 = __int_as_float(c0.y), w1 = __int_as_float(c1.y);
        float w2 = __int_as_float(c2.y), w3 = __int_as_float(c3.y);
        A0.x += w0*v0.x; A0.y += w0*v0.y; A0.z += w0*v0.z; A0.w += w0*v0.w;
        A1.x += w1*v1.x; A1.y += w1*v1.y; A1.z += w1*v1.z; A1.w += w1*v1.w;
        A2.x += w2*v2.x; A2.y += w2*v2.y; A2.z += w2*v2.z; A2.w += w2*v2.w;
        A3.x += w3*v3.x; A3.y += w3*v3.y; A3.z += w3*v3.z; A3.w += w3*v3.w;
    }
    for (; e < end; e += 4) {
        int2 c0 = cwp[e];
        float4 v0 = bf4(*(const ushort4*)&cur[(size_t)c0.x * 64 + q * 4]);
        float w0 = __int_as_float(c0.y);
        A0.x += w0*v0.x; A0.y += w0*v0.y; A0.z += w0*v0.z; A0.w += w0*v0.w;
    }
    A0.x += A1.x + A2.x + A3.x;
    A0.y += A1.y + A2.y + A3.y;
    A0.z += A1.z + A2.z + A3.z;
    A0.w += A1.w + A2.w + A3.w;

    // reduce across the 4 edge groups (lanes differing in bits 4,5)
    A0.x += __shfl_xor(A0.x, 16); A0.y += __shfl_xor(A0.y, 16);
    A0.z += __shfl_xor(A0.z, 16); A0.w += __shfl_xor(A0.w, 16);
    A0.x += __shfl_xor(A0.x, 32); A0.y += __shfl_xor(A0.y, 32);
    A0.z += __shfl_xor(A0.z, 32); A0.w += __shfl_xor(A0.w, 32);

    if (oi < 0) {
        if (g == 0) {
            ushort4 ob = make_ushort4(f2b(A0.x), f2b(A0.y), f2b(A0.z), f2b(A0.w));
            *(ushort4*)&nxt[(size_t)node * 64 + q * 4] = ob;
        }
    } else {
        // gate: s = row . wp  (reduce partial dot across the 16 q-lanes)
        float s = A0.x * wp[q * 4] + A0.y * wp[q * 4 + 1]
                + A0.z * wp[q * 4 + 2] + A0.w * wp[q * 4 + 3];
        s += __shfl_xor(s, 1); s += __shfl_xor(s, 2);
        s += __shfl_xor(s, 4); s += __shfl_xor(s, 8);
        float gate = 1.f / (1.f + __expf(-s));
        if (g == 0) {
            float* op = &out[(size_t)oi * 64 + q * 4];
            float4 prev = *(float4*)op;
            prev.x += gate * A0.x; prev.y += gate * A0.y;
            prev.z += gate * A0.z; prev.w += gate * A0.w;
            *(float4*)op = prev;
        }
    }
}

// ---------------------------------------------------------------------------
// Hop-0 gate: out[i] = sigmoid(h[idx[i]].wp) * h[idx[i]]  (fp32 h, inits out)
// ---------------------------------------------------------------------------
__launch_bounds__(256)
__global__ void gate_gather(const float* __restrict__ h,
                            const int* __restrict__ idx,
                            const float* __restrict__ wp,
                            float* __restrict__ out, int nI)
{
    int gid = blockIdx.x * 256 + threadIdx.x;
    int i = gid >> 6;
    if (i >= nI) return;
    int c = gid & 63;
    int n = idx[i];
    float v = h[(size_t)n * 64 + c];
    float s = v * wp[c];
    #pragma unroll
    for (int off = 32; off > 0; off >>= 1)
        s += __shfl_xor(s, off);
    float gate = 1.f / (1.f + __expf(-s));
    out[gid] = gate * v;
}

extern "C" void kernel_launch(void* const* d_in, const int* in_sizes, int n_in,
                              void* d_out, int out_size, void* d_ws, size_t ws_size,
                              hipStream_t stream) {
    const float* x    = (const float*)d_in[0];
    const int*   esrc = (const int*)d_in[1];
    const int*   edst = (const int*)d_in[2];
    const float* ew   = (const float*)d_in[3];
    const int*   nidx = (const int*)d_in[4];
    const float* W1   = (const float*)d_in[5];
    const float* W2   = (const float*)d_in[6];
    const float* wp   = (const float*)d_in[7];
    float* out = (float*)d_out;

    const int nN = in_sizes[0] / 512;
    const int nE = in_sizes[1];
    const int nI = in_sizes[4];

    // ws: h0 fp32 25.6M | bufA bf16 12.8M | bufB bf16 12.8M | rowptr 0.4M | cwp 12.8M
    float*          h0     = (float*)d_ws;
    unsigned short* bufA   = (unsigned short*)(h0 + (size_t)nN * C);
    unsigned short* bufB   = bufA + (size_t)nN * C;
    int*            rowptr = (int*)(bufB + (size_t)nN * C);
    int2*           cwp    = (int2*)(rowptr + nN);

    // --- CSR build (by dst) ---
    hipMemsetAsync(rowptr, 0, (size_t)nN * sizeof(int), stream);
    count_kernel<<<(nE + 255) / 256, 256, 0, stream>>>(edst, rowptr, nE);
    scan_kernel<<<1, 1024, 0, stream>>>(rowptr, nN);
    fill_kernel<<<(nE + 255) / 256, 256, 0, stream>>>(esrc, edst, ew, rowptr, cwp, nE);

    // --- MLP (fp32 + bf16 h) ---
    mlp_kernel<<<(nN + 63) / 64, 256, 0, stream>>>(x, W1, W2, h0, bufA, nN);

    // hop 0 gate (initializes out, fp32 path)
    gate_gather<<<(nI * 64 + 255) / 256, 256, 0, stream>>>(h0, nidx, wp, out, nI);

    unsigned short* cur = bufA;
    unsigned short* nxt = bufB;
    const int nodeBlocks = (nN + 3) / 4;
    const int idxBlocks  = (nI + 3) / 4;
    for (int k = 0; k < 10; ++k) {
        spmm_fused<<<nodeBlocks + idxBlocks, 256, 0, stream>>>(
            rowptr, cwp, cur, nxt, nidx, wp, out, nN, nI, nodeBlocks);
        unsigned short* tmp = cur; cur = nxt; nxt = tmp;
    }
}